// Round 1
// baseline (337.692 us; speedup 1.0000x reference)
//
#include <hip/hip_runtime.h>

#define B_   4
#define N_   1024
#define FIN  128
#define FOUT 256
#define NH   8
#define ND   32
#define NSL  0.2f

// ---------------- K1: g = h@W, el = g·a_l, er = g·a_r ----------------
__global__ __launch_bounds__(256) void gat_k1(
    const float* __restrict__ h, const float* __restrict__ W,
    const float* __restrict__ a_vec, float* __restrict__ g,
    float* __restrict__ el, float* __restrict__ er)
{
  __shared__ float hs[8][FIN];
  const int t = threadIdx.x;
  const int row0 = blockIdx.x * 8;
  for (int idx = t; idx < 8 * FIN; idx += 256)
    hs[idx >> 7][idx & 127] = h[(size_t)row0 * FIN + idx];
  __syncthreads();

  float acc[8];
#pragma unroll
  for (int r = 0; r < 8; ++r) acc[r] = 0.f;
  const int c = t;  // output column 0..255
#pragma unroll 4
  for (int k = 0; k < FIN; ++k) {
    const float w = W[k * FOUT + c];
#pragma unroll
    for (int r = 0; r < 8; ++r) acc[r] += hs[r][k] * w;
  }

  const int f = c & 31, head = c >> 5;
  const float al = a_vec[f], ar = a_vec[ND + f];
#pragma unroll
  for (int r = 0; r < 8; ++r) {
    g[(size_t)(row0 + r) * FOUT + c] = acc[r];
    float pl = acc[r] * al, pr = acc[r] * ar;
#pragma unroll
    for (int m = 16; m >= 1; m >>= 1) {
      pl += __shfl_xor(pl, m, 32);
      pr += __shfl_xor(pr, m, 32);
    }
    if (f == 0) {
      el[(row0 + r) * NH + head] = pl;
      er[(row0 + r) * NH + head] = pr;
    }
  }
}

// ------- K3: fused masked softmax (no max-sub) + PV, per (b, head, 64-row tile) -------
__global__ __launch_bounds__(128) void gat_k3(
    const int* __restrict__ adj, const float* __restrict__ g,
    const float* __restrict__ el, const float* __restrict__ er,
    float* __restrict__ out)
{
  __shared__ float p_t[64][68];    // p tile [ii][jj], stride 68 (16B-aligned, conflict-free b128)
  __shared__ float gt_t[32][68];   // G^T tile [f][jj]
  __shared__ float el_s[64], er_s[64], den_s[64];

  const int t = threadIdx.x;
  const int b    = blockIdx.x >> 7;
  const int head = (blockIdx.x >> 4) & 7;
  const int it   = blockIdx.x & 15;
  const int i0   = it * 64;

  if (t < 64) {
    el_s[t] = el[(b * N_ + i0 + t) * NH + head];
    den_s[t] = 0.f;
  }

  const int fgrp = t & 7;        // owns f = fgrp + 8q
  const int rgrp = t >> 3;       // owns ii = rgrp + 16r
  const int lane = t & 63, wv = t >> 6;
  const int* adj_base = adj + ((size_t)b * N_ + i0) * N_;

  float acc[4][4];
#pragma unroll
  for (int r = 0; r < 4; ++r)
#pragma unroll
    for (int q = 0; q < 4; ++q) acc[r][q] = 0.f;

  for (int jt = 0; jt < 16; ++jt) {
    const int j0 = jt * 64;
    __syncthreads();  // previous PV done with p_t/gt_t (also covers init stores, iter 0)

    // stage G^T (32 f x 64 jj) via float4 global reads
    for (int idx = t; idx < 512; idx += 128) {
      const int jj = idx >> 3, f4 = (idx & 7) * 4;
      const float4 v = *(const float4*)&g[((size_t)b * N_ + j0 + jj) * FOUT + head * ND + f4];
      gt_t[f4 + 0][jj] = v.x; gt_t[f4 + 1][jj] = v.y;
      gt_t[f4 + 2][jj] = v.z; gt_t[f4 + 3][jj] = v.w;
    }
    if (t < 64) er_s[t] = er[(b * N_ + j0 + t) * NH + head];
    __syncthreads();

    // compute p tile: wave wv handles row ii = 2s+wv, lane = jj
#pragma unroll 4
    for (int s = 0; s < 32; ++s) {
      const int ii = 2 * s + wv;
      float e = el_s[ii] + er_s[lane];
      e = (e >= 0.f) ? e : NSL * e;
      const int a = adj_base[(size_t)ii * N_ + j0 + lane];
      const float p = a ? __expf(e) : 0.f;   // no max-sub: e bounded ~|8|, safe in fp32
      p_t[ii][lane] = p;
      float sum = p;
#pragma unroll
      for (int m = 32; m >= 1; m >>= 1) sum += __shfl_xor(sum, m);
      if (lane == 0) den_s[ii] += sum;
    }
    __syncthreads();

    // PV: acc[r][q] += p_t[ii][jj..jj+3] . gt_t[f][jj..jj+3]
#pragma unroll 4
    for (int jj = 0; jj < 64; jj += 4) {
      float4 av[4], gv[4];
#pragma unroll
      for (int r = 0; r < 4; ++r)
        av[r] = *(const float4*)&p_t[rgrp + 16 * r][jj];
#pragma unroll
      for (int q = 0; q < 4; ++q)
        gv[q] = *(const float4*)&gt_t[fgrp + 8 * q][jj];
#pragma unroll
      for (int r = 0; r < 4; ++r)
#pragma unroll
        for (int q = 0; q < 4; ++q)
          acc[r][q] += av[r].x * gv[q].x + av[r].y * gv[q].y
                     + av[r].z * gv[q].z + av[r].w * gv[q].w;
    }
  }

  // epilogue: normalize, LeakyReLU, store
#pragma unroll
  for (int r = 0; r < 4; ++r) {
    const int ii = rgrp + 16 * r;
    const float inv = 1.f / den_s[ii];
#pragma unroll
    for (int q = 0; q < 4; ++q) {
      const int f = fgrp + 8 * q;
      float v = acc[r][q] * inv;
      v = (v >= 0.f) ? v : NSL * v;
      out[((size_t)b * N_ + i0 + ii) * FOUT + head * ND + f] = v;
    }
  }
}

extern "C" void kernel_launch(void* const* d_in, const int* in_sizes, int n_in,
                              void* d_out, int out_size, void* d_ws, size_t ws_size,
                              hipStream_t stream) {
  const float* h     = (const float*)d_in[0];
  const int*   adj   = (const int*)d_in[1];
  const float* W     = (const float*)d_in[2];
  const float* a_vec = (const float*)d_in[3];
  float* out = (float*)d_out;

  float* g  = (float*)d_ws;                       // B*N*FOUT      = 1,048,576 f
  float* el = g + (size_t)B_ * N_ * FOUT;         // B*N*NH        = 32,768 f
  float* er = el + (size_t)B_ * N_ * NH;          // B*N*NH        = 32,768 f

  gat_k1<<<(B_ * N_) / 8, 256, 0, stream>>>(h, W, a_vec, g, el, er);
  gat_k3<<<B_ * NH * (N_ / 64), 128, 0, stream>>>(adj, g, el, er, out);
}

// Round 2
// 62.958 us; speedup vs baseline: 5.3638x; 5.3638x over previous
//
#include <hip/hip_runtime.h>

#define B_   4
#define N_   1024
#define FIN  128
#define FOUT 256
#define NH   8
#define ND   32
#define NSL  0.2f

typedef _Float16 half8 __attribute__((ext_vector_type(8)));
typedef float f32x4 __attribute__((ext_vector_type(4)));

// ---- K1: g16T[b,head,f][j] = f16(h@W), elT/erT = (g.a_l / g.a_r) transposed ----
__global__ __launch_bounds__(256) void gat_k1(
    const float* __restrict__ h, const float* __restrict__ W,
    const float* __restrict__ a_vec, _Float16* __restrict__ g16,
    float* __restrict__ elt, float* __restrict__ ert)
{
  __shared__ float hs[8][FIN];
  const int t = threadIdx.x;
  const int row0 = blockIdx.x * 8;            // global row in [0,4096)
  for (int idx = t; idx < 8 * FIN; idx += 256)
    hs[idx >> 7][idx & 127] = h[(size_t)row0 * FIN + idx];
  __syncthreads();

  float acc[8];
#pragma unroll
  for (int r = 0; r < 8; ++r) acc[r] = 0.f;
  const int c = t;
#pragma unroll 4
  for (int k = 0; k < FIN; ++k) {
    const float w = W[k * FOUT + c];
#pragma unroll
    for (int r = 0; r < 8; ++r) acc[r] += hs[r][k] * w;
  }

  const int f = c & 31, head = c >> 5;
  const int b = row0 >> 10, n0 = row0 & 1023;

  // g16T chunk: column (head,f), 8 consecutive j
  half8 hv;
#pragma unroll
  for (int r = 0; r < 8; ++r) hv[r] = (_Float16)acc[r];
  *(half8*)&g16[((size_t)(b * NH + head) * ND + f) * N_ + n0] = hv;

  const float al = a_vec[f], ar = a_vec[ND + f];
#pragma unroll
  for (int r = 0; r < 8; ++r) {
    float pl = acc[r] * al, pr = acc[r] * ar;
#pragma unroll
    for (int m = 16; m >= 1; m >>= 1) {
      pl += __shfl_xor(pl, m, 32);
      pr += __shfl_xor(pr, m, 32);
    }
    if (f == 0) {
      elt[(b * NH + head) * N_ + n0 + r] = pl;
      ert[(b * NH + head) * N_ + n0 + r] = pr;
    }
  }
}

// ---- K3: per (b,head,32-row i-tile); 4 waves own (i-half, f-half) 16x16 tiles.
//      D = G^T(f x k) * P^T(k x i) via mfma_f32_16x16x32_f16; no barriers in K-loop.
__global__ __launch_bounds__(256) void gat_k3(
    const int* __restrict__ adj, const _Float16* __restrict__ g16,
    const float* __restrict__ elt, const float* __restrict__ ert,
    float* __restrict__ out)
{
  __shared__ float er_s[N_];

  const int t = threadIdx.x;
  const int it   = blockIdx.x & 31;
  const int head = (blockIdx.x >> 5) & 7;
  const int b    = blockIdx.x >> 8;
  const int i0   = it * 32;
  const int hb   = b * NH + head;

  // stage er (coalesced float4, one per thread)
  *(float4*)&er_s[4 * t] = *(const float4*)&ert[(size_t)hb * N_ + 4 * t];
  __syncthreads();

  const int wv = t >> 6, lane = t & 63;
  const int ih = wv & 1, fh = wv >> 1;     // i-half, f-half
  const int li = lane & 15;                // = A-row f, = B-col i, = D-col i
  const int kg = lane >> 4;                // k-group: k = 8*kg + e

  const float el_i = elt[(size_t)hb * N_ + i0 + ih * 16 + li];
  const int* adjrow = adj + ((size_t)(b * N_ + i0 + ih * 16 + li)) * N_ + kg * 8;
  const _Float16* arow = g16 + ((size_t)hb * ND + fh * 16 + li) * N_ + kg * 8;

  f32x4 acc = {0.f, 0.f, 0.f, 0.f};
  float den = 0.f;

  for (int jt = 0; jt < 16; ++jt) {
    const int j0 = jt * 64;
#pragma unroll
    for (int kh = 0; kh < 2; ++kh) {
      const int k0 = j0 + kh * 32;
      const int4 a0 = *(const int4*)(adjrow + k0);
      const int4 a1 = *(const int4*)(adjrow + k0 + 4);
      const float4 e0 = *(const float4*)&er_s[k0 + kg * 8];
      const float4 e1 = *(const float4*)&er_s[k0 + kg * 8 + 4];
      const half8 Ag = *(const half8*)(arow + k0);

      const int   am[8]  = {a0.x, a0.y, a0.z, a0.w, a1.x, a1.y, a1.z, a1.w};
      const float er8[8] = {e0.x, e0.y, e0.z, e0.w, e1.x, e1.y, e1.z, e1.w};
      half8 Pf;
      float dp = 0.f;
#pragma unroll
      for (int e = 0; e < 8; ++e) {
        float x = el_i + er8[e];
        x = fmaxf(x, NSL * x);               // LeakyReLU == max(x, 0.2x)
        float pv = __expf(x);                // no max-sub: |e| <~ 6, safe
        pv = am[e] ? pv : 0.f;
        dp += pv;
        Pf[e] = (_Float16)pv;
      }
      den += dp;
      acc = __builtin_amdgcn_mfma_f32_16x16x32_f16(Ag, Pf, acc, 0, 0, 0);
    }
  }

  // denominator: sum across the 4 k-groups sharing the same i (= l&15)
  den += __shfl_xor(den, 16);
  den += __shfl_xor(den, 32);
  const float inv = 1.f / den;

  // D[f][i]: row f = 4*kg + r (within f-half), col i = li
#pragma unroll
  for (int r = 0; r < 4; ++r) {
    const int f = fh * 16 + 4 * kg + r;
    float v = acc[r] * inv;
    v = fmaxf(v, NSL * v);
    out[((size_t)(b * N_ + i0 + ih * 16 + li)) * FOUT + head * ND + f] = v;
  }
}

extern "C" void kernel_launch(void* const* d_in, const int* in_sizes, int n_in,
                              void* d_out, int out_size, void* d_ws, size_t ws_size,
                              hipStream_t stream) {
  const float* h     = (const float*)d_in[0];
  const int*   adj   = (const int*)d_in[1];
  const float* W     = (const float*)d_in[2];
  const float* a_vec = (const float*)d_in[3];
  float* out = (float*)d_out;

  _Float16* g16 = (_Float16*)d_ws;                         // B*NH*ND*N = 1,048,576 halves (2 MB)
  float* elt = (float*)(g16 + (size_t)B_ * NH * ND * N_);  // 32768 f
  float* ert = elt + (size_t)B_ * NH * N_;                 // 32768 f

  gat_k1<<<(B_ * N_) / 8, 256, 0, stream>>>(h, W, a_vec, g16, elt, ert);
  gat_k3<<<B_ * NH * (N_ / 32), 256, 0, stream>>>(adj, g16, elt, ert, out);
}

// Round 4
// 54.245 us; speedup vs baseline: 6.2253x; 1.1606x over previous
//
#include <hip/hip_runtime.h>

#define B_    4
#define N_    1024
#define FIN   128
#define FOUT  256
#define NH    8
#define ND    32
#define NSL   0.2f
#define LOG2E 1.44269504088896340736f

typedef _Float16 half8 __attribute__((ext_vector_type(8)));
typedef __fp16 fp16x2 __attribute__((ext_vector_type(2)));
typedef float f32x4 __attribute__((ext_vector_type(4)));

// ---- K1: g16T[hb][f][n] = f16(h@W); elt/ert[hb][n] = LOG2E*(g.a_l / g.a_r) ----
// h rows read via wave-uniform addresses -> scalar loads (SGPR broadcast), no LDS.
__global__ __launch_bounds__(256) void gat_k1(
    const float* __restrict__ h, const float* __restrict__ W,
    const float* __restrict__ a_vec, _Float16* __restrict__ g16,
    float* __restrict__ elt, float* __restrict__ ert)
{
  const int t = threadIdx.x;
  const int row0 = blockIdx.x * 8;
  const float* __restrict__ hrow = h + (size_t)row0 * FIN;

  float acc[8] = {0.f, 0.f, 0.f, 0.f, 0.f, 0.f, 0.f, 0.f};
  const int c = t;
#pragma unroll 4
  for (int k = 0; k < FIN; ++k) {
    const float w = W[k * FOUT + c];
#pragma unroll
    for (int r = 0; r < 8; ++r) acc[r] += hrow[r * FIN + k] * w;  // hrow[..] uniform -> s_load
  }

  const int f = c & 31, head = c >> 5;
  const int b = row0 >> 10, n0 = row0 & 1023;

  half8 hv;
#pragma unroll
  for (int r = 0; r < 8; ++r) hv[r] = (_Float16)acc[r];
  *(half8*)&g16[((size_t)(b * NH + head) * ND + f) * N_ + n0] = hv;

  const float al = a_vec[f] * LOG2E, ar = a_vec[ND + f] * LOG2E;
#pragma unroll
  for (int r = 0; r < 8; ++r) {
    float pl = acc[r] * al, pr = acc[r] * ar;
#pragma unroll
    for (int m = 16; m >= 1; m >>= 1) {
      pl += __shfl_xor(pl, m, 32);
      pr += __shfl_xor(pr, m, 32);
    }
    if (f == 0) {
      elt[(b * NH + head) * N_ + n0 + r] = pl;
      ert[(b * NH + head) * N_ + n0 + r] = pr;
    }
  }
}

// ---- K3: block = (b, head, 16-row i-tile); 4 waves each: 16 i x 32 f x 256 j ----
// No P-gen redundancy, den via ones-MFMA, j-split combined through LDS epilogue.
__global__ __launch_bounds__(256) void gat_k3(
    const int* __restrict__ adj, const _Float16* __restrict__ g16,
    const float* __restrict__ elt, const float* __restrict__ ert,
    float* __restrict__ out)
{
  __shared__ float er_s[N_];
  __shared__ float dpart[4][32][17];
  __shared__ float denp[4][16];

  const int t = threadIdx.x;
  const int it   = blockIdx.x & 63;
  const int head = (blockIdx.x >> 6) & 7;
  const int b    = blockIdx.x >> 9;
  const int i0   = it * 16;
  const int hb   = b * NH + head;

  *(float4*)&er_s[4 * t] = *(const float4*)&ert[(size_t)hb * N_ + 4 * t];
  __syncthreads();

  const int wv = t >> 6, lane = t & 63;
  const int li = lane & 15, kg = lane >> 4;

  const float el_i = elt[(size_t)hb * N_ + i0 + li];
  const int* __restrict__ adjrow =
      adj + ((size_t)(b * N_ + i0 + li)) * N_ + wv * 256 + kg * 8;
  const _Float16* __restrict__ arow0 =
      g16 + ((size_t)hb * ND + li) * N_ + wv * 256 + kg * 8;
  const _Float16* __restrict__ arow1 = arow0 + (size_t)16 * N_;

  f32x4 acc0 = {0.f, 0.f, 0.f, 0.f};
  f32x4 acc1 = {0.f, 0.f, 0.f, 0.f};
  f32x4 accd = {0.f, 0.f, 0.f, 0.f};
  const half8 ones = {(_Float16)1.f, (_Float16)1.f, (_Float16)1.f, (_Float16)1.f,
                      (_Float16)1.f, (_Float16)1.f, (_Float16)1.f, (_Float16)1.f};

#pragma unroll 2
  for (int jt = 0; jt < 8; ++jt) {
    const int k0 = jt * 32;
    const int4 a0 = *(const int4*)(adjrow + k0);
    const int4 a1 = *(const int4*)(adjrow + k0 + 4);
    const int ks = wv * 256 + k0 + kg * 8;
    const float4 e0 = *(const float4*)&er_s[ks];
    const float4 e1 = *(const float4*)&er_s[ks + 4];
    const half8 Ag0 = *(const half8*)(arow0 + k0);
    const half8 Ag1 = *(const half8*)(arow1 + k0);

    const int   am[8]  = {a0.x, a0.y, a0.z, a0.w, a1.x, a1.y, a1.z, a1.w};
    const float er8[8] = {e0.x, e0.y, e0.z, e0.w, e1.x, e1.y, e1.z, e1.w};
    float pv[8];
#pragma unroll
    for (int e = 0; e < 8; ++e) {
      float x = el_i + er8[e];            // already log2-scaled
      x = fmaxf(x, NSL * x);              // LeakyReLU (scale>0 commutes)
      float p;
      asm("v_exp_f32 %0, %1" : "=v"(p) : "v"(x));  // 2^x
      pv[e] = am[e] ? p : 0.f;
    }

    union { half8 h8; unsigned u[4]; } P;
#pragma unroll
    for (int q = 0; q < 4; ++q) {
      union { fp16x2 h; unsigned u; } cv;
      cv.h = __builtin_amdgcn_cvt_pkrtz(pv[2 * q], pv[2 * q + 1]);
      P.u[q] = cv.u;
    }

    acc0 = __builtin_amdgcn_mfma_f32_16x16x32_f16(Ag0, P.h8, acc0, 0, 0, 0);
    acc1 = __builtin_amdgcn_mfma_f32_16x16x32_f16(Ag1, P.h8, acc1, 0, 0, 0);
    accd = __builtin_amdgcn_mfma_f32_16x16x32_f16(ones, P.h8, accd, 0, 0, 0);
  }

  // stash partials: D rows f = (fh*16 + 4*kg + r), col i = li; den replicated in all rows
#pragma unroll
  for (int r = 0; r < 4; ++r) {
    dpart[wv][4 * kg + r][li]      = acc0[r];
    dpart[wv][16 + 4 * kg + r][li] = acc1[r];
  }
  if (lane < 16) denp[wv][lane] = accd[0];
  __syncthreads();

  // combine 4 j-partials, normalize, LeakyReLU, store
  for (int o = t; o < 512; o += 256) {
    const int f = o & 31, ii = o >> 5;
    const float s  = dpart[0][f][ii] + dpart[1][f][ii]
                   + dpart[2][f][ii] + dpart[3][f][ii];
    const float dn = denp[0][ii] + denp[1][ii] + denp[2][ii] + denp[3][ii];
    float v = s / dn;
    v = fmaxf(v, NSL * v);
    out[((size_t)(b * N_ + i0 + ii)) * FOUT + head * ND + f] = v;
  }
}

extern "C" void kernel_launch(void* const* d_in, const int* in_sizes, int n_in,
                              void* d_out, int out_size, void* d_ws, size_t ws_size,
                              hipStream_t stream) {
  const float* h     = (const float*)d_in[0];
  const int*   adj   = (const int*)d_in[1];
  const float* W     = (const float*)d_in[2];
  const float* a_vec = (const float*)d_in[3];
  float* out = (float*)d_out;

  _Float16* g16 = (_Float16*)d_ws;                         // B*NH*ND*N halves (2 MB)
  float* elt = (float*)(g16 + (size_t)B_ * NH * ND * N_);  // 32768 f
  float* ert = elt + (size_t)B_ * NH * N_;                 // 32768 f

  gat_k1<<<(B_ * N_) / 8, 256, 0, stream>>>(h, W, a_vec, g16, elt, ert);
  gat_k3<<<B_ * NH * (N_ / 16), 256, 0, stream>>>(adj, g16, elt, ert, out);
}